// Round 6
// baseline (473.382 us; speedup 1.0000x reference)
//
#include <hip/hip_runtime.h>
#include <stdint.h>

#define M_DIM 8192
#define N_DIM 4096
#define K_DIM 4096
#define BM 256
#define BN 256
#define BKS 64                    // K-slab bytes (i8) per pipeline stage
#define NSLAB (K_DIM / BKS)       // 64 slabs
#define SLOT_BYTES (256 * BKS)    // 16 KB per matrix per ring slot

typedef int i32x4  __attribute__((ext_vector_type(4)));
typedef int i32x16 __attribute__((ext_vector_type(16)));

__device__ __forceinline__ void async_copy16(const void* g, void* l) {
    __builtin_amdgcn_global_load_lds(
        (const __attribute__((address_space(1))) void*)g,
        (__attribute__((address_space(3))) void*)l, 16, 0, 0);
}

// ---- fused pass 1: blocks [0,1024) do |w| partial sums; blocks [1024,9216)
// ---- do per-row x absmax + i8 quantize (xquant is gamma-independent).
__global__ __launch_bounds__(256) void prep_kernel(
    const float4* __restrict__ w,
    const float4* __restrict__ x,
    double* __restrict__ partials,
    char4* __restrict__ xq,
    float* __restrict__ xscale)
{
    const int lane = threadIdx.x & 63;
    const int wave = threadIdx.x >> 6;

    if (blockIdx.x < 1024) {
        int base = blockIdx.x * 4096 + threadIdx.x;
        float s = 0.f;
        #pragma unroll
        for (int i = 0; i < 16; i++) {
            float4 v = w[base + i * 256];
            s += fabsf(v.x) + fabsf(v.y) + fabsf(v.z) + fabsf(v.w);
        }
        double d = (double)s;
        #pragma unroll
        for (int off = 32; off > 0; off >>= 1) d += __shfl_down(d, off, 64);
        __shared__ double wsum[4];
        if (lane == 0) wsum[wave] = d;
        __syncthreads();
        if (threadIdx.x == 0)
            partials[blockIdx.x] = (wsum[0] + wsum[1]) + (wsum[2] + wsum[3]);
    } else {
        const int row = blockIdx.x - 1024;
        const float4* xr = x + (size_t)row * (K_DIM / 4);
        float4 v[4];
        float m = 0.f;
        #pragma unroll
        for (int i = 0; i < 4; i++) {
            v[i] = xr[threadIdx.x + i * 256];
            m = fmaxf(m, fmaxf(fmaxf(fabsf(v[i].x), fabsf(v[i].y)),
                               fmaxf(fabsf(v[i].z), fabsf(v[i].w))));
        }
        #pragma unroll
        for (int off = 32; off > 0; off >>= 1) m = fmaxf(m, __shfl_down(m, off, 64));
        __shared__ float wmax[4];
        if (lane == 0) wmax[wave] = m;
        __syncthreads();
        const float mx = fmaxf(fmaxf(wmax[0], wmax[1]), fmaxf(wmax[2], wmax[3]));
        const float scale = fmaxf(mx * (1.f / 127.f), 1e-30f);
        const float inv = 1.f / scale;
        if (threadIdx.x == 0) xscale[row] = scale;
        char4* oq = xq + (size_t)row * (K_DIM / 4);
        #pragma unroll
        for (int i = 0; i < 4; i++) {
            char4 o;
            o.x = (signed char)fminf(fmaxf(rintf(v[i].x * inv), -127.f), 127.f);
            o.y = (signed char)fminf(fmaxf(rintf(v[i].y * inv), -127.f), 127.f);
            o.z = (signed char)fminf(fmaxf(rintf(v[i].z * inv), -127.f), 127.f);
            o.w = (signed char)fminf(fmaxf(rintf(v[i].w * inv), -127.f), 127.f);
            oq[threadIdx.x + i * 256] = o;
        }
    }
}

// ---- fused pass 2: gamma reduce (bitwise-identical order) + w quantize ----
__global__ __launch_bounds__(256) void wquant_kernel(
    const double* __restrict__ partials,
    const float4* __restrict__ w,
    char4* __restrict__ qw)
{
    const int lane = threadIdx.x & 63;
    const int wave = threadIdx.x >> 6;
    double d = partials[threadIdx.x] + partials[threadIdx.x + 256] +
               partials[threadIdx.x + 512] + partials[threadIdx.x + 768];
    #pragma unroll
    for (int off = 32; off > 0; off >>= 1) d += __shfl_down(d, off, 64);
    __shared__ double wsum[4];
    if (lane == 0) wsum[wave] = d;
    __shared__ float gsh;
    __syncthreads();
    if (threadIdx.x == 0) {
        double total = (wsum[0] + wsum[1]) + (wsum[2] + wsum[3]);
        gsh = fmaxf((float)(total * (1.0 / 16777216.0)), 1e-8f);
    }
    __syncthreads();
    const float gamma = gsh;

    int base = blockIdx.x * 4096 + threadIdx.x;
    #pragma unroll
    for (int j = 0; j < 16; j++) {
        float4 v = w[base + j * 256];
        char4 o;
        o.x = (signed char)fminf(fmaxf(rintf(v.x / gamma), -1.f), 1.f);
        o.y = (signed char)fminf(fmaxf(rintf(v.y / gamma), -1.f), 1.f);
        o.z = (signed char)fminf(fmaxf(rintf(v.z / gamma), -1.f), 1.f);
        o.w = (signed char)fminf(fmaxf(rintf(v.w / gamma), -1.f), 1.f);
        qw[base + j * 256] = o;
    }
}

// ---- pass 3: C[M,N] = scale[m] * (Xq[M,K] @ Qw[N,K]^T)_i32 + bias ----
//
// R6 design (post-mortem of R0-R5: barrier-lockstep + fair round-robin LDS
// service makes per-slab read-time and MFMA-time ADD; six schedules all
// measured as the serial sum). Two structural changes:
//
//  1. Wave tile 128x128 (4 waves / 256 thr, block 256x256): LDS reads drop
//     96 -> 64 KB per CU-slab. mfma_i32_32x32x32_i8 (4404 TOPS ubench,
//     half the instruction count). acc[4][4] x i32x16 = 256 VGPRs.
//  2. Register double-buffer across slabs: slab t+1's 16 ds_read_b128 are
//     issued BEFORE slab t's 32-MFMA cluster, lgkmcnt(0) AFTER it. Read
//     latency (~770 cy CU-wide) hides under the MFMA window (~1170 cy)
//     regardless of wave convergence. 1 wave/SIMD is fine: the pipeline is
//     intra-wave. __launch_bounds__(256,1) for the full VGPR budget.
//
// Ring-4 LDS slots (4 x 32 KB = 128 KB), stage distance 3. Sync ledger:
//  - reads at iter t target slab t+1 (slot (t+1)&3). Residency: end-of-(t-1)
//    boundary vmcnt(8) leaves only the newest 8 gloads (slab t+2), retiring
//    slab t+1; s_barrier publishes all waves' staging. The memory-clobber
//    asm prevents the compiler hoisting reads across the boundary.
//  - WAR: stage(t+3) at iter t writes slot (t-1)&3. Its readers (slab t-1
//    ds_reads) completed at each wave's lgkmcnt(0) in iter t-1, before the
//    end-of-(t-1) barrier, which precedes the stage issue.
//  - tail: end of t=60 -> vmcnt(8) (retires slab 62); end of t=61 ->
//    vmcnt(0) (retires 63); t=62,63 need no boundary.
//
// Swizzle (new involution for 64-B rows, both sides): phys 16B-chunk
// p = c ^ (row&3). Read pattern (32-row column-slab per fragment) covers
// all 8 bank-quads evenly in both k-steps -> conflict-free (paper-checked).
// Staging source side: csw = (l&3) ^ ((l>>2)&3); LDS dest stays linear.
__global__ __launch_bounds__(256, 1) void gemm_kernel(
    const char* __restrict__ xq,       // [M,K] i8
    const char* __restrict__ qw,       // [N,K] i8 ternary
    const float* __restrict__ xscale,  // [M]
    const float* __restrict__ bias,    // [N]
    float* __restrict__ out)           // [M,N] fp32
{
    __shared__ __align__(16) char As[4][SLOT_BYTES];   // 64 KB
    __shared__ __align__(16) char Bs[4][SLOT_BYTES];   // 64 KB

    const int tid  = threadIdx.x;
    const int wave = tid >> 6;
    const int lane = tid & 63;
    const int wm   = (wave >> 1) * 128;   // 0 or 128
    const int wn   = (wave & 1) * 128;    // 0 or 128
    const int l31  = lane & 31;
    const int lhi  = lane >> 5;           // k-half within a 32-B k-step

    const int bm = blockIdx.y * BM;
    const int bn = blockIdx.x * BN;

    // ---- staging: wave w covers A rows [w*64,w*64+64) and B rows same,
    // 4 rounds each of 1 KB (16 rows x 64 B). Lane l -> dest row
    // rbase+(l>>2), dest chunk l&3; source chunk csw = (l&3) ^ (row&3).
    const int rsub = lane >> 2;                        // 0..15
    const int csw  = (lane & 3) ^ ((lane >> 2) & 3);
    const char* gA[4];
    const char* gB[4];
    int ldsOff[4];
    #pragma unroll
    for (int j = 0; j < 4; j++) {
        const int r = wave * 64 + j * 16 + rsub;
        gA[j] = xq + (size_t)(bm + r) * K_DIM + csw * 16;
        gB[j] = qw + (size_t)(bn + r) * K_DIM + csw * 16;
        ldsOff[j] = (wave * 64 + j * 16) * BKS;
    }

    i32x16 acc[4][4];
    const i32x16 zz = {0,0,0,0,0,0,0,0,0,0,0,0,0,0,0,0};
    #pragma unroll
    for (int i = 0; i < 4; i++)
        #pragma unroll
        for (int j = 0; j < 4; j++) acc[i][j] = zz;

    // ---- read-side addressing. Fragment (f, ks): lane reads 16 B at
    // row = base + f*32 + l31, logical chunk c = ks*2 + lhi,
    // phys chunk p = c ^ (row&3) = c ^ (l31&3).
    const int ch0 = ((0 + lhi) ^ (l31 & 3)) * 16;      // ks=0
    const int ch1 = ((2 + lhi) ^ (l31 & 3)) * 16;      // ks=1
    const int rowA = (wm + l31) * BKS;
    const int rowB = (wn + l31) * BKS;

    i32x4 bufA0[4][2], bufB0[4][2], bufA1[4][2], bufB1[4][2];

    auto stage_slab = [&](int ts, int slot) {
        #pragma unroll
        for (int j = 0; j < 4; j++) {
            async_copy16(gA[j] + (size_t)ts * BKS, &As[slot][ldsOff[j]]);
            async_copy16(gB[j] + (size_t)ts * BKS, &Bs[slot][ldsOff[j]]);
        }
    };

    auto read_frags = [&](i32x4 (&rA)[4][2], i32x4 (&rB)[4][2], int slot) {
        const char* Ab = As[slot];
        const char* Bb = Bs[slot];
        #pragma unroll
        for (int f = 0; f < 4; f++) {
            rA[f][0] = *(const i32x4*)(Ab + rowA + f * 2048 + ch0);
            rA[f][1] = *(const i32x4*)(Ab + rowA + f * 2048 + ch1);
            rB[f][0] = *(const i32x4*)(Bb + rowB + f * 2048 + ch0);
            rB[f][1] = *(const i32x4*)(Bb + rowB + f * 2048 + ch1);
        }
    };

    auto mfma_all = [&](i32x4 (&cA)[4][2], i32x4 (&cB)[4][2]) {
        __builtin_amdgcn_s_setprio(1);
        #pragma unroll
        for (int ks = 0; ks < 2; ks++)
            #pragma unroll
            for (int mi = 0; mi < 4; mi++)
                #pragma unroll
                for (int ni = 0; ni < 4; ni++)
                    acc[mi][ni] = __builtin_amdgcn_mfma_i32_32x32x32_i8(
                        cA[mi][ks], cB[ni][ks], acc[mi][ni], 0, 0, 0);
        __builtin_amdgcn_s_setprio(0);
    };

    // ---- prologue: stage slabs 0,1,2; slab 0 resident; read its frags ----
    stage_slab(0, 0);
    stage_slab(1, 1);
    stage_slab(2, 2);
    asm volatile("s_waitcnt vmcnt(16)" ::: "memory");  // slab 0 resident
    __builtin_amdgcn_s_barrier();
    read_frags(bufA0, bufB0, 0);

    // ---- main loop: t = 0..59 (unrolled x4: static slots + buffer parity)
    for (int tb = 0; tb < 60; tb += 4) {
        #pragma unroll
        for (int u = 0; u < 4; u++) {
            const int ts = tb + u + 3;
            stage_slab(ts, (u + 3) & 3);
            if (u & 1) read_frags(bufA0, bufB0, (u + 1) & 3);
            else       read_frags(bufA1, bufB1, (u + 1) & 3);
            __builtin_amdgcn_sched_barrier(0);
            if (u & 1) mfma_all(bufA1, bufB1);
            else       mfma_all(bufA0, bufB0);
            asm volatile("s_waitcnt lgkmcnt(0)" ::: "memory");
            __builtin_amdgcn_sched_barrier(0);
            asm volatile("s_waitcnt vmcnt(8)" ::: "memory");
            __builtin_amdgcn_s_barrier();
        }
    }

    // ---- peeled t = 60 (stage slab 63), 61, 62, 63 ----
    stage_slab(63, 3);                       // t = 60: slot (60+3)&3 = 3
    read_frags(bufA1, bufB1, 1);             // slab 61
    __builtin_amdgcn_sched_barrier(0);
    mfma_all(bufA0, bufB0);                  // slab 60
    asm volatile("s_waitcnt lgkmcnt(0)" ::: "memory");
    __builtin_amdgcn_sched_barrier(0);
    asm volatile("s_waitcnt vmcnt(8)" ::: "memory");   // retire slab 62
    __builtin_amdgcn_s_barrier();

    read_frags(bufA0, bufB0, 2);             // t = 61: slab 62
    __builtin_amdgcn_sched_barrier(0);
    mfma_all(bufA1, bufB1);                  // slab 61
    asm volatile("s_waitcnt lgkmcnt(0)" ::: "memory");
    __builtin_amdgcn_sched_barrier(0);
    asm volatile("s_waitcnt vmcnt(0)" ::: "memory");   // retire slab 63
    __builtin_amdgcn_s_barrier();

    read_frags(bufA1, bufB1, 3);             // t = 62: slab 63
    __builtin_amdgcn_sched_barrier(0);
    mfma_all(bufA0, bufB0);                  // slab 62
    asm volatile("s_waitcnt lgkmcnt(0)" ::: "memory");
    __builtin_amdgcn_sched_barrier(0);

    mfma_all(bufA1, bufB1);                  // t = 63

    // ---- epilogue: 32x32 C/D layout: col = lane&31,
    // ---- row = (reg&3) + 8*(reg>>2) + 4*(lane>>5)  (m74/m101)
    float bl[4];
    #pragma unroll
    for (int ni = 0; ni < 4; ni++) bl[ni] = bias[bn + wn + ni * 32 + l31];

    #pragma unroll
    for (int mi = 0; mi < 4; mi++) {
        #pragma unroll
        for (int r = 0; r < 16; r++) {
            const int grow = bm + wm + mi * 32 + (r & 3) + 8 * (r >> 2) + 4 * lhi;
            const float sc = xscale[grow];
            float* orow = out + (size_t)grow * N_DIM + bn + wn;
            #pragma unroll
            for (int ni = 0; ni < 4; ni++)
                orow[ni * 32 + l31] = sc * (float)acc[mi][ni][r] + bl[ni];
        }
    }
}

extern "C" void kernel_launch(void* const* d_in, const int* in_sizes, int n_in,
                              void* d_out, int out_size, void* d_ws, size_t ws_size,
                              hipStream_t stream) {
    const float* x    = (const float*)d_in[0];   // [4,2048,4096] = [8192,4096]
    const float* w    = (const float*)d_in[1];   // [4096,4096]
    const float* bias = (const float*)d_in[2];   // [4096]
    float* out = (float*)d_out;

    char* ws = (char*)d_ws;
    char*   xq       = ws;                                        // 32 MB
    char*   qw       = ws + (size_t)M_DIM * K_DIM;                // 16 MB
    float*  xscale   = (float*)(qw + (size_t)N_DIM * K_DIM);      // 32 KB
    double* partials = (double*)(xscale + M_DIM);                 // 8 KB

    prep_kernel<<<1024 + M_DIM, 256, 0, stream>>>(
        (const float4*)w, (const float4*)x, partials, (char4*)xq, xscale);
    wquant_kernel<<<1024, 256, 0, stream>>>(partials, (const float4*)w, (char4*)qw);

    dim3 grid(N_DIM / BN, M_DIM / BM);   // (16, 32) = 512 blocks
    gemm_kernel<<<grid, 256, 0, stream>>>(xq, qw, xscale, bias, out);
}

// Round 7
// 451.037 us; speedup vs baseline: 1.0495x; 1.0495x over previous
//
#include <hip/hip_runtime.h>
#include <stdint.h>

#define M_DIM 8192
#define N_DIM 4096
#define K_DIM 4096
#define BM 256
#define BN 256
#define BKS 64                    // K-slab bytes (i8) per pipeline stage
#define NSLAB (K_DIM / BKS)       // 64 slabs
#define SLOT_BYTES (256 * BKS)    // 16 KB per matrix per ring slot

typedef int i32x4  __attribute__((ext_vector_type(4)));
typedef int i32x16 __attribute__((ext_vector_type(16)));

__device__ __forceinline__ void async_copy16(const void* g, void* l) {
    __builtin_amdgcn_global_load_lds(
        (const __attribute__((address_space(1))) void*)g,
        (__attribute__((address_space(3))) void*)l, 16, 0, 0);
}

// ---- fused pass 1: blocks [0,1024) do |w| partial sums; blocks [1024,9216)
// ---- do per-row x absmax + i8 quantize (xquant is gamma-independent).
__global__ __launch_bounds__(256) void prep_kernel(
    const float4* __restrict__ w,
    const float4* __restrict__ x,
    double* __restrict__ partials,
    char4* __restrict__ xq,
    float* __restrict__ xscale)
{
    const int lane = threadIdx.x & 63;
    const int wave = threadIdx.x >> 6;

    if (blockIdx.x < 1024) {
        int base = blockIdx.x * 4096 + threadIdx.x;
        float s = 0.f;
        #pragma unroll
        for (int i = 0; i < 16; i++) {
            float4 v = w[base + i * 256];
            s += fabsf(v.x) + fabsf(v.y) + fabsf(v.z) + fabsf(v.w);
        }
        double d = (double)s;
        #pragma unroll
        for (int off = 32; off > 0; off >>= 1) d += __shfl_down(d, off, 64);
        __shared__ double wsum[4];
        if (lane == 0) wsum[wave] = d;
        __syncthreads();
        if (threadIdx.x == 0)
            partials[blockIdx.x] = (wsum[0] + wsum[1]) + (wsum[2] + wsum[3]);
    } else {
        const int row = blockIdx.x - 1024;
        const float4* xr = x + (size_t)row * (K_DIM / 4);
        float4 v[4];
        float m = 0.f;
        #pragma unroll
        for (int i = 0; i < 4; i++) {
            v[i] = xr[threadIdx.x + i * 256];
            m = fmaxf(m, fmaxf(fmaxf(fabsf(v[i].x), fabsf(v[i].y)),
                               fmaxf(fabsf(v[i].z), fabsf(v[i].w))));
        }
        #pragma unroll
        for (int off = 32; off > 0; off >>= 1) m = fmaxf(m, __shfl_down(m, off, 64));
        __shared__ float wmax[4];
        if (lane == 0) wmax[wave] = m;
        __syncthreads();
        const float mx = fmaxf(fmaxf(wmax[0], wmax[1]), fmaxf(wmax[2], wmax[3]));
        const float scale = fmaxf(mx * (1.f / 127.f), 1e-30f);
        const float inv = 1.f / scale;
        if (threadIdx.x == 0) xscale[row] = scale;
        char4* oq = xq + (size_t)row * (K_DIM / 4);
        #pragma unroll
        for (int i = 0; i < 4; i++) {
            char4 o;
            o.x = (signed char)fminf(fmaxf(rintf(v[i].x * inv), -127.f), 127.f);
            o.y = (signed char)fminf(fmaxf(rintf(v[i].y * inv), -127.f), 127.f);
            o.z = (signed char)fminf(fmaxf(rintf(v[i].z * inv), -127.f), 127.f);
            o.w = (signed char)fminf(fmaxf(rintf(v[i].w * inv), -127.f), 127.f);
            oq[threadIdx.x + i * 256] = o;
        }
    }
}

// ---- fused pass 2: gamma reduce (bitwise-identical order) + w quantize ----
__global__ __launch_bounds__(256) void wquant_kernel(
    const double* __restrict__ partials,
    const float4* __restrict__ w,
    char4* __restrict__ qw)
{
    const int lane = threadIdx.x & 63;
    const int wave = threadIdx.x >> 6;
    double d = partials[threadIdx.x] + partials[threadIdx.x + 256] +
               partials[threadIdx.x + 512] + partials[threadIdx.x + 768];
    #pragma unroll
    for (int off = 32; off > 0; off >>= 1) d += __shfl_down(d, off, 64);
    __shared__ double wsum[4];
    if (lane == 0) wsum[wave] = d;
    __shared__ float gsh;
    __syncthreads();
    if (threadIdx.x == 0) {
        double total = (wsum[0] + wsum[1]) + (wsum[2] + wsum[3]);
        gsh = fmaxf((float)(total * (1.0 / 16777216.0)), 1e-8f);
    }
    __syncthreads();
    const float gamma = gsh;

    int base = blockIdx.x * 4096 + threadIdx.x;
    #pragma unroll
    for (int j = 0; j < 16; j++) {
        float4 v = w[base + j * 256];
        char4 o;
        o.x = (signed char)fminf(fmaxf(rintf(v.x / gamma), -1.f), 1.f);
        o.y = (signed char)fminf(fmaxf(rintf(v.y / gamma), -1.f), 1.f);
        o.z = (signed char)fminf(fmaxf(rintf(v.z / gamma), -1.f), 1.f);
        o.w = (signed char)fminf(fmaxf(rintf(v.w / gamma), -1.f), 1.f);
        qw[base + j * 256] = o;
    }
}

// ---- pass 3: C[M,N] = scale[m] * (Xq[M,K] @ Qw[N,K]^T)_i32 + bias ----
//
// R7 = R6 with ONLY the swizzle fixed (isolating A/B on the bank-conflict
// variable). R6's p = c ^ (row&3) put consecutive-8-lane groups on 4 of 8
// bank-quads (2-way serialize, 2.5e7 conflict cycles). Correct involution
// (same one R0-R5 measured 0 conflicts with):
//     phys 16B-chunk p = c ^ ((row>>1)&3)
// Within 8 consecutive lanes (rows r..r+7): even rows -> (row>>1)&3 takes
// all 4 values -> quads 0..3 once each; odd rows -> quads 4..7 once each.
// All 8 quads exactly once per 8-lane group -> conflict-free b128.
//
// Everything else identical to R6:
//  1. Wave tile 128x128 (4 waves / 256 thr, block 256x256), LDS reads
//     64 KB per CU-slab (vs 96 at R1). mfma_i32_32x32x32_i8, acc[4][4]
//     x i32x16 (AGPR-resident).
//  2. Register double-buffer across slabs: slab t+1's 16 ds_read_b128
//     issue BEFORE slab t's 32-MFMA cluster; lgkmcnt(0) AFTER it. Read
//     latency hides under the ~1170-cy MFMA window regardless of wave
//     convergence. __launch_bounds__(256,1): 1 wave/SIMD by design.
//
// Ring-4 LDS slots (128 KB), stage distance 3. Sync ledger:
//  - reads at iter t target slab t+1 (slot (t+1)&3); end-of-(t-1) vmcnt(8)
//    retired slab t+1's gloads; barrier published them.
//  - WAR: stage(t+3) at iter t writes slot (t-1)&3; its readers finished at
//    iter t-1's lgkmcnt(0), before the end-of-(t-1) barrier.
//  - tail: end of t=60 -> vmcnt(8); end of t=61 -> vmcnt(0).
// Staging source side (matching inverse, derivation: dest row r = rbase +
// (l>>2), dest chunk l&3 holds logical (l&3)^((r>>1)&3); (r>>1)&3 =
// (l>>3)&3 since rbase is a multiple of 16): csw = (l&3) ^ ((l>>3)&3).
__global__ __launch_bounds__(256, 1) void gemm_kernel(
    const char* __restrict__ xq,       // [M,K] i8
    const char* __restrict__ qw,       // [N,K] i8 ternary
    const float* __restrict__ xscale,  // [M]
    const float* __restrict__ bias,    // [N]
    float* __restrict__ out)           // [M,N] fp32
{
    __shared__ __align__(16) char As[4][SLOT_BYTES];   // 64 KB
    __shared__ __align__(16) char Bs[4][SLOT_BYTES];   // 64 KB

    const int tid  = threadIdx.x;
    const int wave = tid >> 6;
    const int lane = tid & 63;
    const int wm   = (wave >> 1) * 128;   // 0 or 128
    const int wn   = (wave & 1) * 128;    // 0 or 128
    const int l31  = lane & 31;
    const int lhi  = lane >> 5;           // k-half within a 32-B k-step

    const int bm = blockIdx.y * BM;
    const int bn = blockIdx.x * BN;

    // ---- staging: wave w covers A rows [w*64,w*64+64) and B rows same,
    // 4 rounds each of 1 KB (16 rows x 64 B). Lane l -> dest row
    // rbase+(l>>2), dest chunk l&3; source chunk csw = (l&3)^((l>>3)&3).
    const int rsub = lane >> 2;                        // 0..15
    const int csw  = (lane & 3) ^ ((lane >> 3) & 3);
    const char* gA[4];
    const char* gB[4];
    int ldsOff[4];
    #pragma unroll
    for (int j = 0; j < 4; j++) {
        const int r = wave * 64 + j * 16 + rsub;
        gA[j] = xq + (size_t)(bm + r) * K_DIM + csw * 16;
        gB[j] = qw + (size_t)(bn + r) * K_DIM + csw * 16;
        ldsOff[j] = (wave * 64 + j * 16) * BKS;
    }

    i32x16 acc[4][4];
    const i32x16 zz = {0,0,0,0,0,0,0,0,0,0,0,0,0,0,0,0};
    #pragma unroll
    for (int i = 0; i < 4; i++)
        #pragma unroll
        for (int j = 0; j < 4; j++) acc[i][j] = zz;

    // ---- read-side addressing. Fragment (f, ks): lane reads 16 B at
    // row = base + f*32 + l31 (base multiple of 32), logical chunk
    // c = ks*2 + lhi, phys chunk p = c ^ ((row>>1)&3) = c ^ ((l31>>1)&3).
    const int ch0 = ((0 + lhi) ^ ((l31 >> 1) & 3)) * 16;   // ks=0
    const int ch1 = ((2 + lhi) ^ ((l31 >> 1) & 3)) * 16;   // ks=1
    const int rowA = (wm + l31) * BKS;
    const int rowB = (wn + l31) * BKS;

    i32x4 bufA0[4][2], bufB0[4][2], bufA1[4][2], bufB1[4][2];

    auto stage_slab = [&](int ts, int slot) {
        #pragma unroll
        for (int j = 0; j < 4; j++) {
            async_copy16(gA[j] + (size_t)ts * BKS, &As[slot][ldsOff[j]]);
            async_copy16(gB[j] + (size_t)ts * BKS, &Bs[slot][ldsOff[j]]);
        }
    };

    auto read_frags = [&](i32x4 (&rA)[4][2], i32x4 (&rB)[4][2], int slot) {
        const char* Ab = As[slot];
        const char* Bb = Bs[slot];
        #pragma unroll
        for (int f = 0; f < 4; f++) {
            rA[f][0] = *(const i32x4*)(Ab + rowA + f * 2048 + ch0);
            rA[f][1] = *(const i32x4*)(Ab + rowA + f * 2048 + ch1);
            rB[f][0] = *(const i32x4*)(Bb + rowB + f * 2048 + ch0);
            rB[f][1] = *(const i32x4*)(Bb + rowB + f * 2048 + ch1);
        }
    };

    auto mfma_all = [&](i32x4 (&cA)[4][2], i32x4 (&cB)[4][2]) {
        __builtin_amdgcn_s_setprio(1);
        #pragma unroll
        for (int ks = 0; ks < 2; ks++)
            #pragma unroll
            for (int mi = 0; mi < 4; mi++)
                #pragma unroll
                for (int ni = 0; ni < 4; ni++)
                    acc[mi][ni] = __builtin_amdgcn_mfma_i32_32x32x32_i8(
                        cA[mi][ks], cB[ni][ks], acc[mi][ni], 0, 0, 0);
        __builtin_amdgcn_s_setprio(0);
    };

    // ---- prologue: stage slabs 0,1,2; slab 0 resident; read its frags ----
    stage_slab(0, 0);
    stage_slab(1, 1);
    stage_slab(2, 2);
    asm volatile("s_waitcnt vmcnt(16)" ::: "memory");  // slab 0 resident
    __builtin_amdgcn_s_barrier();
    read_frags(bufA0, bufB0, 0);

    // ---- main loop: t = 0..59 (unrolled x4: static slots + buffer parity)
    for (int tb = 0; tb < 60; tb += 4) {
        #pragma unroll
        for (int u = 0; u < 4; u++) {
            const int ts = tb + u + 3;
            stage_slab(ts, (u + 3) & 3);
            if (u & 1) read_frags(bufA0, bufB0, (u + 1) & 3);
            else       read_frags(bufA1, bufB1, (u + 1) & 3);
            __builtin_amdgcn_sched_barrier(0);
            if (u & 1) mfma_all(bufA1, bufB1);
            else       mfma_all(bufA0, bufB0);
            asm volatile("s_waitcnt lgkmcnt(0)" ::: "memory");
            __builtin_amdgcn_sched_barrier(0);
            asm volatile("s_waitcnt vmcnt(8)" ::: "memory");
            __builtin_amdgcn_s_barrier();
        }
    }

    // ---- peeled t = 60 (stage slab 63), 61, 62, 63 ----
    stage_slab(63, 3);                       // t = 60: slot (60+3)&3 = 3
    read_frags(bufA1, bufB1, 1);             // slab 61
    __builtin_amdgcn_sched_barrier(0);
    mfma_all(bufA0, bufB0);                  // slab 60
    asm volatile("s_waitcnt lgkmcnt(0)" ::: "memory");
    __builtin_amdgcn_sched_barrier(0);
    asm volatile("s_waitcnt vmcnt(8)" ::: "memory");   // retire slab 62
    __builtin_amdgcn_s_barrier();

    read_frags(bufA0, bufB0, 2);             // t = 61: slab 62
    __builtin_amdgcn_sched_barrier(0);
    mfma_all(bufA1, bufB1);                  // slab 61
    asm volatile("s_waitcnt lgkmcnt(0)" ::: "memory");
    __builtin_amdgcn_sched_barrier(0);
    asm volatile("s_waitcnt vmcnt(0)" ::: "memory");   // retire slab 63
    __builtin_amdgcn_s_barrier();

    read_frags(bufA1, bufB1, 3);             // t = 62: slab 63
    __builtin_amdgcn_sched_barrier(0);
    mfma_all(bufA0, bufB0);                  // slab 62
    asm volatile("s_waitcnt lgkmcnt(0)" ::: "memory");
    __builtin_amdgcn_sched_barrier(0);

    mfma_all(bufA1, bufB1);                  // t = 63

    // ---- epilogue: 32x32 C/D layout: col = lane&31,
    // ---- row = (reg&3) + 8*(reg>>2) + 4*(lane>>5)  (m74/m101)
    float bl[4];
    #pragma unroll
    for (int ni = 0; ni < 4; ni++) bl[ni] = bias[bn + wn + ni * 32 + l31];

    #pragma unroll
    for (int mi = 0; mi < 4; mi++) {
        #pragma unroll
        for (int r = 0; r < 16; r++) {
            const int grow = bm + wm + mi * 32 + (r & 3) + 8 * (r >> 2) + 4 * lhi;
            const float sc = xscale[grow];
            float* orow = out + (size_t)grow * N_DIM + bn + wn;
            #pragma unroll
            for (int ni = 0; ni < 4; ni++)
                orow[ni * 32 + l31] = sc * (float)acc[mi][ni][r] + bl[ni];
        }
    }
}

extern "C" void kernel_launch(void* const* d_in, const int* in_sizes, int n_in,
                              void* d_out, int out_size, void* d_ws, size_t ws_size,
                              hipStream_t stream) {
    const float* x    = (const float*)d_in[0];   // [4,2048,4096] = [8192,4096]
    const float* w    = (const float*)d_in[1];   // [4096,4096]
    const float* bias = (const float*)d_in[2];   // [4096]
    float* out = (float*)d_out;

    char* ws = (char*)d_ws;
    char*   xq       = ws;                                        // 32 MB
    char*   qw       = ws + (size_t)M_DIM * K_DIM;                // 16 MB
    float*  xscale   = (float*)(qw + (size_t)N_DIM * K_DIM);      // 32 KB
    double* partials = (double*)(xscale + M_DIM);                 // 8 KB

    prep_kernel<<<1024 + M_DIM, 256, 0, stream>>>(
        (const float4*)w, (const float4*)x, partials, (char4*)xq, xscale);
    wquant_kernel<<<1024, 256, 0, stream>>>(partials, (const float4*)w, (char4*)qw);

    dim3 grid(N_DIM / BN, M_DIM / BM);   // (16, 32) = 512 blocks
    gemm_kernel<<<grid, 256, 0, stream>>>(xq, qw, xscale, bias, out);
}